// Round 6
// baseline (170.258 us; speedup 1.0000x reference)
//
#include <hip/hip_runtime.h>
#include <math.h>

#define BB 4
#define TT 2048
#define NEMB 256
#define NH 8
#define HD 32

typedef __attribute__((ext_vector_type(8))) short bf8;   // 8 x bf16 (4 VGPRs)
typedef __attribute__((ext_vector_type(4))) float f4;    // MFMA C/D

static __device__ __forceinline__ unsigned short f2bf(float f) {
    union { float f; unsigned u; } v; v.f = f;
    unsigned r = v.u + 0x7FFF + ((v.u >> 16) & 1);       // RNE
    return (unsigned short)(r >> 16);
}
static __device__ __forceinline__ float bf2f(unsigned short s) {
    union { unsigned u; float f; } v; v.u = ((unsigned)s) << 16;
    return v.f;
}

// DPP cross-lane move within 16-lane rows (VALU pipe, not LDS pipe)
template <int CTRL>
static __device__ __forceinline__ float dppmv(float x) {
    return __int_as_float(__builtin_amdgcn_mov_dpp(__float_as_int(x), CTRL, 0xF, 0xF, true));
}
static __device__ __forceinline__ float rowmax16(float x) {
    x = fmaxf(x, dppmv<0xB1>(x));
    x = fmaxf(x, dppmv<0x4E>(x));
    x = fmaxf(x, dppmv<0x124>(x));
    x = fmaxf(x, dppmv<0x128>(x));
    return x;
}
static __device__ __forceinline__ float rowsum16(float x) {
    x += dppmv<0xB1>(x);
    x += dppmv<0x4E>(x);
    x += dppmv<0x124>(x);
    x += dppmv<0x128>(x);
    return x;
}

// ---------------- fused prep: x->bf16, pe->bf16, w_attn^T, w_proj^T ----------
static __device__ __forceinline__ void tcvt_body(const float* __restrict__ src,
                                                 unsigned short* __restrict__ dst,
                                                 int R, int C, int gx, int gy,
                                                 float (*t)[65], int tid) {
    const int c0 = gx * 64, r0 = gy * 64;
    #pragma unroll
    for (int p = 0; p < 4; ++p) {
        const int i = tid + p * 256;
        const int r = i >> 4, c4 = (i & 15) * 4;
        const float4 v = *(const float4*)(src + (long)(r0 + r) * C + c0 + c4);
        t[r][c4] = v.x; t[r][c4+1] = v.y; t[r][c4+2] = v.z; t[r][c4+3] = v.w;
    }
    __syncthreads();
    #pragma unroll
    for (int p = 0; p < 4; ++p) {
        const int i = tid + p * 256;
        const int cr = i >> 4, r4 = (i & 15) * 4;
        ushort4 vv;
        vv.x = f2bf(t[r4+0][cr]); vv.y = f2bf(t[r4+1][cr]);
        vv.z = f2bf(t[r4+2][cr]); vv.w = f2bf(t[r4+3][cr]);
        *(ushort4*)(dst + (long)(c0 + cr) * R + r0 + r4) = vv;
    }
}

__global__ __launch_bounds__(256) void prep(const float* __restrict__ x,
                                            unsigned short* __restrict__ xb,
                                            const float* __restrict__ pe,
                                            unsigned short* __restrict__ peb,
                                            const float* __restrict__ wa,
                                            unsigned short* __restrict__ waT,
                                            const float* __restrict__ wp,
                                            unsigned short* __restrict__ wpT) {
    __shared__ float t[64][65];
    const int bx = blockIdx.x, tid = threadIdx.x;
    if (bx < 2048) {
        const long i = (long)bx * 256 + tid;
        const float4 v = ((const float4*)x)[i];
        ushort4 o; o.x = f2bf(v.x); o.y = f2bf(v.y); o.z = f2bf(v.z); o.w = f2bf(v.w);
        ((ushort4*)xb)[i] = o;
    } else if (bx < 2560) {
        const long i = (long)(bx - 2048) * 256 + tid;
        const float4 v = ((const float4*)pe)[i];
        ushort4 o; o.x = f2bf(v.x); o.y = f2bf(v.y); o.z = f2bf(v.z); o.w = f2bf(v.w);
        ((ushort4*)peb)[i] = o;
    } else if (bx < 2608) {
        const int lo = bx - 2560;                 // 48 blocks: w_attn [256][768] -> [768][256]
        tcvt_body(wa, waT, 256, 768, lo % 12, lo / 12, t, tid);
    } else {
        const int lo = bx - 2608;                 // 16 blocks: w_proj [256][256] -> transpose
        tcvt_body(wp, wpT, 256, 256, lo % 4, lo / 4, t, tid);
    }
}

// ---------------- Kernel A: MFMA qkv GEMM + packed epilogue ------------------
// Q is pre-scaled by (1/sqrt(32)) * log2(e) so attention can use exp2.
__global__ __launch_bounds__(256) void qkv_mfma(const unsigned short* __restrict__ Ag,
                                                const unsigned short* __restrict__ Bg,
                                                unsigned short* __restrict__ Kb,
                                                unsigned short* __restrict__ Qb,
                                                unsigned short* __restrict__ Vt) {
    __shared__ unsigned short sm[13824];             // 27648 B
    unsigned short* As = sm;                         // [128][72]
    unsigned short* Bs = sm + 9216;                  // [64][72]
    const int tid = threadIdx.x;
    const int wv = tid >> 6, L = tid & 63;
    const int l15 = L & 15, q = L >> 4;
    const int n0 = blockIdx.x * 64;
    const int m0 = blockIdx.y * 128;

    f4 acc[2][4];
    #pragma unroll
    for (int mt = 0; mt < 2; ++mt)
        #pragma unroll
        for (int nt = 0; nt < 4; ++nt) acc[mt][nt] = (f4){0.f,0.f,0.f,0.f};

    for (int kc = 0; kc < 4; ++kc) {
        const int k0 = kc * 64;
        __syncthreads();
        #pragma unroll
        for (int p = 0; p < 4; ++p) {
            const int i = tid + p * 256;
            const int r = i >> 3, c = i & 7;
            *(bf8*)(As + r * 72 + c * 8) = *(const bf8*)(Ag + (long)(m0 + r) * 256 + k0 + c * 8);
        }
        #pragma unroll
        for (int p = 0; p < 2; ++p) {
            const int i = tid + p * 256;
            const int r = i >> 3, c = i & 7;
            *(bf8*)(Bs + r * 72 + c * 8) = *(const bf8*)(Bg + (long)(n0 + r) * 256 + k0 + c * 8);
        }
        __syncthreads();
        #pragma unroll
        for (int kk = 0; kk < 2; ++kk) {
            const bf8 a0 = *(const bf8*)(As + (wv * 32 + l15) * 72 + kk * 32 + q * 8);
            const bf8 a1 = *(const bf8*)(As + (wv * 32 + 16 + l15) * 72 + kk * 32 + q * 8);
            #pragma unroll
            for (int nt = 0; nt < 4; ++nt) {
                const bf8 bb = *(const bf8*)(Bs + (nt * 16 + l15) * 72 + kk * 32 + q * 8);
                acc[0][nt] = __builtin_amdgcn_mfma_f32_16x16x32_bf16(a0, bb, acc[0][nt], 0, 0, 0);
                acc[1][nt] = __builtin_amdgcn_mfma_f32_16x16x32_bf16(a1, bb, acc[1][nt], 0, 0, 0);
            }
        }
    }

    const int sec = n0 >> 8;                         // 0=K,1=Q,2=V (block-uniform)
    #pragma unroll
    for (int mt = 0; mt < 2; ++mt) {
        const int gm = m0 + wv * 32 + mt * 16 + q * 4;
        const int b = gm >> 11, tb = gm & 2047;
        #pragma unroll
        for (int nt = 0; nt < 4; ++nt) {
            const int gn = n0 + nt * 16 + l15;
            const int cc = gn & 255, h = cc >> 5, d = cc & 31;
            const long bh = (long)b * NH + h;
            const f4 a = acc[mt][nt];
            if (sec == 2) {
                ushort4 vv;
                vv.x = f2bf(a[0]); vv.y = f2bf(a[1]); vv.z = f2bf(a[2]); vv.w = f2bf(a[3]);
                *(ushort4*)(Vt + (bh * HD + d) * TT + tb) = vv;
            } else if (sec == 1) {
                #pragma unroll
                for (int r = 0; r < 4; ++r)
                    Qb[(bh * TT + tb + r) * HD + d] = f2bf(a[r] * 0.25506655788696527f);
            } else {
                #pragma unroll
                for (int r = 0; r < 4; ++r)
                    Kb[(bh * TT + tb + r) * HD + d] = f2bf(a[r]);
            }
        }
    }
}

// ---------------- Kernel B: MFMA flash attention, s-split x2 -----------------
// grid.x = 32: pair = bx>>1 (t-tiles {pair, 31-pair}), sblk = bx&1 picks
// jt ∈ {sblk, sblk+2, ...}. Each block emits normalized partial O + (m,l).
__global__ __launch_bounds__(256) void attn_kernel(const unsigned short* __restrict__ Kb,
                                                   const unsigned short* __restrict__ Qb,
                                                   const unsigned short* __restrict__ Vtg,
                                                   const unsigned short* __restrict__ peb,
                                                   unsigned short* __restrict__ po,
                                                   float* __restrict__ pm,
                                                   float* __restrict__ pl) {
    __shared__ unsigned short lds[14592];            // 29184 B
    unsigned short* Ks  = lds;                       // [64][40]  K tile
    unsigned short* PEs = lds + 2560;                // [128][40] pe band
    unsigned short* Vts = lds + 7680;                // [32][72]  V^T tile
    unsigned short* Psw = lds + 9984 + (threadIdx.x >> 6) * 1152;  // [16][72] per wave

    const int tid = threadIdx.x;
    const int wv  = tid >> 6;
    const int L   = tid & 63;
    const int l15 = L & 15;
    const int q   = L >> 4;
    const int pair = blockIdx.x >> 1;
    const int sblk = blockIdx.x & 1;
    const int h = blockIdx.y, b = blockIdx.z;
    const long bh = (long)b * NH + h;
    const unsigned short* Kg = Kb  + bh * TT * HD;
    const unsigned short* Qg = Qb  + bh * TT * HD;
    const unsigned short* Vg = Vtg + bh * HD * TT;
    const unsigned short* Pg = peb + (long)h * TT * HD;

    const int krow = tid >> 2, kc = tid & 3;
    const int vrow = tid >> 3, vc = tid & 7;
    const f4 z4 = {0.f, 0.f, 0.f, 0.f};

    for (int half = 0; half < 2; ++half) {
        const int itile = half ? 31 - pair : pair;
        const int t0 = itile * 64;

        const bf8 aq = *(const bf8*)(Qg + (t0 + wv * 16 + l15) * HD + q * 8);
        f4 o0 = z4, o1 = z4;
        float m_st[4] = {-1e30f, -1e30f, -1e30f, -1e30f};
        float l_st[4] = {0.f, 0.f, 0.f, 0.f};

        for (int jt = sblk; jt <= itile; jt += 2) {
            const int s0 = jt * 64;
            const int ubase = TT - 64 - t0 + s0;
            __syncthreads();
            *(bf8*)(Ks  + krow * 40 + kc * 8) = *(const bf8*)(Kg + (s0 + krow) * HD + kc * 8);
            *(bf8*)(Vts + vrow * 72 + vc * 8) = *(const bf8*)(Vg + vrow * TT + s0 + vc * 8);
            #pragma unroll
            for (int kk = 0; kk < 2; ++kk) {
                const int i  = tid + kk * 256;
                const int pr = i >> 2, pc = i & 3;
                const int u  = ubase + pr;
                bf8 val = {0,0,0,0,0,0,0,0};
                if (u < TT) val = *(const bf8*)(Pg + (long)u * HD + pc * 8);
                *(bf8*)(PEs + pr * 40 + pc * 8) = val;
            }
            __syncthreads();

            f4 sa[4], ra[5];
            #pragma unroll
            for (int nt = 0; nt < 4; ++nt) {
                const bf8 bk = *(const bf8*)(Ks + (nt * 16 + l15) * 40 + q * 8);
                sa[nt] = __builtin_amdgcn_mfma_f32_16x16x32_bf16(aq, bk, z4, 0, 0, 0);
            }
            const int pebase = 48 - 16 * wv;
            #pragma unroll
            for (int nt = 0; nt < 5; ++nt) {
                const bf8 bp = *(const bf8*)(PEs + (pebase + nt * 16 + l15) * 40 + q * 8);
                ra[nt] = __builtin_amdgcn_mfma_f32_16x16x32_bf16(aq, bp, z4, 0, 0, 0);
            }

            // ---- skew gather: pack (ra[nb],ra[nb+1]) as bf16x2 -> ONE shuffle ----
            unsigned short rb[5][4];
            #pragma unroll
            for (int nt = 0; nt < 5; ++nt)
                #pragma unroll
                for (int r = 0; r < 4; ++r) rb[nt][r] = f2bf(ra[nt][r]);
            #pragma unroll
            for (int nb = 0; nb < 4; ++nb) {
                #pragma unroll
                for (int r = 0; r < 4; ++r) {
                    const unsigned packed = (unsigned)rb[nb][r] | ((unsigned)rb[nb + 1][r] << 16);
                    const int shift = 15 - 4 * q - r;          // 0..15
                    const int tcol  = l15 + shift;             // 0..30
                    const int src   = (q << 4) | (tcol & 15);
                    const unsigned v = (unsigned)__shfl((int)packed, src);
                    const unsigned sel = (tcol < 16) ? (v << 16) : (v & 0xFFFF0000u);
                    sa[nb][r] += __int_as_float((int)sel);
                }
            }

            if (jt == itile) {
                #pragma unroll
                for (int nb = 0; nb < 4; ++nb)
                    #pragma unroll
                    for (int r = 0; r < 4; ++r) {
                        const int s_l = nb * 16 + l15;
                        const int t_l = wv * 16 + 4 * q + r;
                        if (s_l > t_l) sa[nb][r] = -1e30f;
                    }
            }

            // ---- online softmax (exp2 domain); reductions on VALU via DPP ----
            float corr[4];
            #pragma unroll
            for (int r = 0; r < 4; ++r) {
                float mx = fmaxf(fmaxf(sa[0][r], sa[1][r]), fmaxf(sa[2][r], sa[3][r]));
                mx = rowmax16(mx);
                const float mn = fmaxf(m_st[r], mx);
                corr[r] = exp2f(m_st[r] - mn);
                m_st[r] = mn;
                float rs = 0.f;
                #pragma unroll
                for (int nb = 0; nb < 4; ++nb) {
                    const float p = exp2f(sa[nb][r] - mn);
                    rs += p;
                    Psw[(4 * q + r) * 72 + nb * 16 + l15] = f2bf(p);
                }
                rs = rowsum16(rs);
                l_st[r] = l_st[r] * corr[r] + rs;
            }
            #pragma unroll
            for (int r = 0; r < 4; ++r) { o0[r] *= corr[r]; o1[r] *= corr[r]; }

            #pragma unroll
            for (int ks = 0; ks < 2; ++ks) {
                const bf8 ap  = *(const bf8*)(Psw + l15 * 72 + ks * 32 + q * 8);
                const bf8 bv0 = *(const bf8*)(Vts + l15 * 72 + ks * 32 + q * 8);
                const bf8 bv1 = *(const bf8*)(Vts + (16 + l15) * 72 + ks * 32 + q * 8);
                o0 = __builtin_amdgcn_mfma_f32_16x16x32_bf16(ap, bv0, o0, 0, 0, 0);
                o1 = __builtin_amdgcn_mfma_f32_16x16x32_bf16(ap, bv1, o1, 0, 0, 0);
            }
        }

        // ---- partial epilogue: normalized O (bf16) + m,l per row ----
        const long pt = (bh * 32 + itile) * 2 + sblk;
        unsigned short* pob = po + pt * 2048;
        #pragma unroll
        for (int r = 0; r < 4; ++r) {
            const float inv = (l_st[r] > 0.f) ? (1.0f / l_st[r]) : 0.f;
            const int row = wv * 16 + 4 * q + r;
            pob[row * 32 + l15]      = f2bf(o0[r] * inv);
            pob[row * 32 + 16 + l15] = f2bf(o1[r] * inv);
            if (l15 == 0) {
                pm[pt * 64 + row] = m_st[r];
                pl[pt * 64 + row] = l_st[r];
            }
        }
    }
}

// ---------------- merge the two s-split partials -> bf16 att -----------------
__global__ __launch_bounds__(256) void attn_merge(const unsigned short* __restrict__ po,
                                                  const float* __restrict__ pm,
                                                  const float* __restrict__ pl,
                                                  unsigned short* __restrict__ attb) {
    const int i = blockIdx.x * 256 + threadIdx.x;    // 524288 quads
    const int d4   = i & 7;
    const int row  = (i >> 3) & 63;
    const int tile = (i >> 9) & 31;
    const int bh   = i >> 14;                        // 0..31
    const int h = bh & 7, b = bh >> 3;
    const long pt0 = ((long)bh * 32 + tile) * 2;
    const float m0 = pm[pt0 * 64 + row], m1 = pm[(pt0 + 1) * 64 + row];
    const float l0 = pl[pt0 * 64 + row], l1 = pl[(pt0 + 1) * 64 + row];
    const float M  = fmaxf(m0, m1);
    const float w0 = exp2f(m0 - M) * l0;
    const float w1 = exp2f(m1 - M) * l1;
    const float inv = 1.0f / (w0 + w1);
    const ushort4 a = *(const ushort4*)(po + pt0 * 2048 + row * 32 + d4 * 4);
    const ushort4 c = *(const ushort4*)(po + (pt0 + 1) * 2048 + row * 32 + d4 * 4);
    ushort4 o;
    o.x = f2bf((w0 * bf2f(a.x) + w1 * bf2f(c.x)) * inv);
    o.y = f2bf((w0 * bf2f(a.y) + w1 * bf2f(c.y)) * inv);
    o.z = f2bf((w0 * bf2f(a.z) + w1 * bf2f(c.z)) * inv);
    o.w = f2bf((w0 * bf2f(a.w) + w1 * bf2f(c.w)) * inv);
    const int t = tile * 64 + row;
    *(ushort4*)(attb + ((long)(b * TT + t)) * NEMB + h * HD + d4 * 4) = o;
}

// ---------------- Kernel C: MFMA proj GEMM + bias ----------------------------
__global__ __launch_bounds__(256) void proj_mfma(const unsigned short* __restrict__ Ag,
                                                 const unsigned short* __restrict__ Bg,
                                                 const float* __restrict__ bias,
                                                 float* __restrict__ out) {
    __shared__ unsigned short sm[13824];
    unsigned short* As = sm;                         // [128][72]
    unsigned short* Bs = sm + 9216;                  // [64][72]
    const int tid = threadIdx.x;
    const int wv = tid >> 6, L = tid & 63;
    const int l15 = L & 15, q = L >> 4;
    const int n0 = blockIdx.x * 64;
    const int m0 = blockIdx.y * 128;

    f4 acc[2][4];
    #pragma unroll
    for (int mt = 0; mt < 2; ++mt)
        #pragma unroll
        for (int nt = 0; nt < 4; ++nt) acc[mt][nt] = (f4){0.f,0.f,0.f,0.f};

    for (int kc = 0; kc < 4; ++kc) {
        const int k0 = kc * 64;
        __syncthreads();
        #pragma unroll
        for (int p = 0; p < 4; ++p) {
            const int i = tid + p * 256;
            const int r = i >> 3, c = i & 7;
            *(bf8*)(As + r * 72 + c * 8) = *(const bf8*)(Ag + (long)(m0 + r) * 256 + k0 + c * 8);
        }
        #pragma unroll
        for (int p = 0; p < 2; ++p) {
            const int i = tid + p * 256;
            const int r = i >> 3, c = i & 7;
            *(bf8*)(Bs + r * 72 + c * 8) = *(const bf8*)(Bg + (long)(n0 + r) * 256 + k0 + c * 8);
        }
        __syncthreads();
        #pragma unroll
        for (int kk = 0; kk < 2; ++kk) {
            const bf8 a0 = *(const bf8*)(As + (wv * 32 + l15) * 72 + kk * 32 + q * 8);
            const bf8 a1 = *(const bf8*)(As + (wv * 32 + 16 + l15) * 72 + kk * 32 + q * 8);
            #pragma unroll
            for (int nt = 0; nt < 4; ++nt) {
                const bf8 bb = *(const bf8*)(Bs + (nt * 16 + l15) * 72 + kk * 32 + q * 8);
                acc[0][nt] = __builtin_amdgcn_mfma_f32_16x16x32_bf16(a0, bb, acc[0][nt], 0, 0, 0);
                acc[1][nt] = __builtin_amdgcn_mfma_f32_16x16x32_bf16(a1, bb, acc[1][nt], 0, 0, 0);
            }
        }
    }

    #pragma unroll
    for (int mt = 0; mt < 2; ++mt) {
        const int gm = m0 + wv * 32 + mt * 16 + q * 4;
        #pragma unroll
        for (int nt = 0; nt < 4; ++nt) {
            const int gn = n0 + nt * 16 + l15;
            const float bv = bias[gn];
            #pragma unroll
            for (int r = 0; r < 4; ++r)
                out[(long)(gm + r) * NEMB + gn] = acc[mt][nt][r] + bv;
        }
    }
}

extern "C" void kernel_launch(void* const* d_in, const int* in_sizes, int n_in,
                              void* d_out, int out_size, void* d_ws, size_t ws_size,
                              hipStream_t stream) {
    const float* x      = (const float*)d_in[0];
    const float* w_attn = (const float*)d_in[1];
    const float* pe     = (const float*)d_in[2];
    const float* w_proj = (const float*)d_in[3];
    const float* b_proj = (const float*)d_in[4];
    float* out = (float*)d_out;

    char* base = (char*)d_ws;
    unsigned short* xb   = (unsigned short*)(base);                        // 4 MB
    unsigned short* Kb   = (unsigned short*)(base + ( 4u << 20));          // 4 MB
    unsigned short* Qb   = (unsigned short*)(base + ( 8u << 20));          // 4 MB
    unsigned short* Vt   = (unsigned short*)(base + (12u << 20));          // 4 MB
    unsigned short* attb = (unsigned short*)(base + (16u << 20));          // 4 MB
    unsigned short* peb  = (unsigned short*)(base + (20u << 20));          // 1 MB
    unsigned short* waT  = (unsigned short*)(base + (21u << 20));          // 384 KB
    unsigned short* wpT  = (unsigned short*)(base + (43u << 19));          // 128 KB @21.5MB
    unsigned short* po   = (unsigned short*)(base + (22u << 20));          // 8 MB
    float*          pm   = (float*)        (base + (30u << 20));           // 512 KB
    float*          pl   = (float*)        (base + (61u << 19));           // 512 KB @30.5MB

    prep<<<dim3(2624), 256, 0, stream>>>(x, xb, pe, peb, w_attn, waT, w_proj, wpT);
    qkv_mfma<<<dim3(12, 64), 256, 0, stream>>>(xb, waT, Kb, Qb, Vt);
    attn_kernel<<<dim3(32, NH, BB), 256, 0, stream>>>(Kb, Qb, Vt, peb, po, pm, pl);
    attn_merge<<<dim3(2048), 256, 0, stream>>>(po, pm, pl, attb);
    proj_mfma<<<dim3(4, 64), 256, 0, stream>>>(attb, wpT, b_proj, out);
}

// Round 7
// 152.965 us; speedup vs baseline: 1.1131x; 1.1131x over previous
//
#include <hip/hip_runtime.h>
#include <math.h>

#define BB 4
#define TT 2048
#define TTP 2112   // TT + 64 zero pad rows per head (pe)
#define NEMB 256
#define NH 8
#define HD 32

typedef __attribute__((ext_vector_type(8))) short bf8;   // 8 x bf16 (4 VGPRs)
typedef __attribute__((ext_vector_type(4))) float f4;    // MFMA C/D

static __device__ __forceinline__ unsigned short f2bf(float f) {
    union { float f; unsigned u; } v; v.f = f;
    unsigned r = v.u + 0x7FFF + ((v.u >> 16) & 1);       // RNE
    return (unsigned short)(r >> 16);
}
static __device__ __forceinline__ float bf2f(unsigned short s) {
    union { unsigned u; float f; } v; v.u = ((unsigned)s) << 16;
    return v.f;
}

// DPP cross-lane move within 16-lane rows (VALU pipe)
template <int CTRL>
static __device__ __forceinline__ float dppmv(float x) {
    return __int_as_float(__builtin_amdgcn_mov_dpp(__float_as_int(x), CTRL, 0xF, 0xF, true));
}
static __device__ __forceinline__ float rowsum16(float x) {
    x += dppmv<0xB1>(x);
    x += dppmv<0x4E>(x);
    x += dppmv<0x124>(x);
    x += dppmv<0x128>(x);
    return x;
}

// ---------------- fused prep: pe->bf16 (+zero pad), w_attn^T, w_proj^T -------
static __device__ __forceinline__ void tcvt_body(const float* __restrict__ src,
                                                 unsigned short* __restrict__ dst,
                                                 int R, int C, int gx, int gy,
                                                 float (*t)[65], int tid) {
    const int c0 = gx * 64, r0 = gy * 64;
    #pragma unroll
    for (int p = 0; p < 4; ++p) {
        const int i = tid + p * 256;
        const int r = i >> 4, c4 = (i & 15) * 4;
        const float4 v = *(const float4*)(src + (long)(r0 + r) * C + c0 + c4);
        t[r][c4] = v.x; t[r][c4+1] = v.y; t[r][c4+2] = v.z; t[r][c4+3] = v.w;
    }
    __syncthreads();
    #pragma unroll
    for (int p = 0; p < 4; ++p) {
        const int i = tid + p * 256;
        const int cr = i >> 4, r4 = (i & 15) * 4;
        ushort4 vv;
        vv.x = f2bf(t[r4+0][cr]); vv.y = f2bf(t[r4+1][cr]);
        vv.z = f2bf(t[r4+2][cr]); vv.w = f2bf(t[r4+3][cr]);
        *(ushort4*)(dst + (long)(c0 + cr) * R + r0 + r4) = vv;
    }
}

__global__ __launch_bounds__(256) void prep(const float* __restrict__ pe,
                                            unsigned short* __restrict__ peb,
                                            const float* __restrict__ wa,
                                            unsigned short* __restrict__ waT,
                                            const float* __restrict__ wp,
                                            unsigned short* __restrict__ wpT) {
    __shared__ float t[64][65];
    const int bx = blockIdx.x, tid = threadIdx.x;
    if (bx < 528) {                              // pe [8][2048][32] -> [8][2112][32] bf16, pad=0
        const int idx4 = bx * 256 + tid;         // ushort4 granules over [8][2112][8]
        const int h   = idx4 / 16896;
        const int rem = idx4 - h * 16896;
        const int u   = rem >> 3;
        const int d4  = (rem & 7) * 4;
        ushort4 o = make_ushort4(0, 0, 0, 0);
        if (u < TT) {
            const float4 v = *(const float4*)(pe + ((long)(h * TT + u)) * HD + d4);
            o.x = f2bf(v.x); o.y = f2bf(v.y); o.z = f2bf(v.z); o.w = f2bf(v.w);
        }
        *(ushort4*)(peb + ((long)(h * TTP + u)) * HD + d4) = o;
    } else if (bx < 576) {
        const int lo = bx - 528;                 // 48 blocks: w_attn [256][768] -> [768][256]
        tcvt_body(wa, waT, 256, 768, lo % 12, lo / 12, t, tid);
    } else {
        const int lo = bx - 576;                 // 16 blocks: w_proj transpose
        tcvt_body(wp, wpT, 256, 256, lo % 4, lo / 4, t, tid);
    }
}

// ---------------- Kernel A: MFMA qkv GEMM, fp32 A inline-converted -----------
// Q pre-scaled by (1/sqrt(32)) * log2(e) so attention uses raw exp2.
__global__ __launch_bounds__(256) void qkv_mfma(const float* __restrict__ xg,
                                                const unsigned short* __restrict__ Bg,
                                                unsigned short* __restrict__ Kb,
                                                unsigned short* __restrict__ Qb,
                                                unsigned short* __restrict__ Vt) {
    __shared__ unsigned short sm[13824];             // 27648 B
    unsigned short* As = sm;                         // [128][72]
    unsigned short* Bs = sm + 9216;                  // [64][72]
    const int tid = threadIdx.x;
    const int wv = tid >> 6, L = tid & 63;
    const int l15 = L & 15, q = L >> 4;
    const int n0 = blockIdx.x * 64;
    const int m0 = blockIdx.y * 128;

    f4 acc[2][4];
    #pragma unroll
    for (int mt = 0; mt < 2; ++mt)
        #pragma unroll
        for (int nt = 0; nt < 4; ++nt) acc[mt][nt] = (f4){0.f,0.f,0.f,0.f};

    for (int kc = 0; kc < 4; ++kc) {
        const int k0 = kc * 64;
        __syncthreads();
        #pragma unroll
        for (int p = 0; p < 4; ++p) {
            const int i = tid + p * 256;
            const int r = i >> 3, c = i & 7;
            const float4 va = *(const float4*)(xg + (long)(m0 + r) * 256 + k0 + c * 8);
            const float4 vb = *(const float4*)(xg + (long)(m0 + r) * 256 + k0 + c * 8 + 4);
            ushort4 lo, hi;
            lo.x = f2bf(va.x); lo.y = f2bf(va.y); lo.z = f2bf(va.z); lo.w = f2bf(va.w);
            hi.x = f2bf(vb.x); hi.y = f2bf(vb.y); hi.z = f2bf(vb.z); hi.w = f2bf(vb.w);
            *(ushort4*)(As + r * 72 + c * 8)     = lo;
            *(ushort4*)(As + r * 72 + c * 8 + 4) = hi;
        }
        #pragma unroll
        for (int p = 0; p < 2; ++p) {
            const int i = tid + p * 256;
            const int r = i >> 3, c = i & 7;
            *(bf8*)(Bs + r * 72 + c * 8) = *(const bf8*)(Bg + (long)(n0 + r) * 256 + k0 + c * 8);
        }
        __syncthreads();
        #pragma unroll
        for (int kk = 0; kk < 2; ++kk) {
            const bf8 a0 = *(const bf8*)(As + (wv * 32 + l15) * 72 + kk * 32 + q * 8);
            const bf8 a1 = *(const bf8*)(As + (wv * 32 + 16 + l15) * 72 + kk * 32 + q * 8);
            #pragma unroll
            for (int nt = 0; nt < 4; ++nt) {
                const bf8 bb = *(const bf8*)(Bs + (nt * 16 + l15) * 72 + kk * 32 + q * 8);
                acc[0][nt] = __builtin_amdgcn_mfma_f32_16x16x32_bf16(a0, bb, acc[0][nt], 0, 0, 0);
                acc[1][nt] = __builtin_amdgcn_mfma_f32_16x16x32_bf16(a1, bb, acc[1][nt], 0, 0, 0);
            }
        }
    }

    const int sec = n0 >> 8;                         // 0=K,1=Q,2=V
    #pragma unroll
    for (int mt = 0; mt < 2; ++mt) {
        const int gm = m0 + wv * 32 + mt * 16 + q * 4;
        const int b = gm >> 11, tb = gm & 2047;
        #pragma unroll
        for (int nt = 0; nt < 4; ++nt) {
            const int gn = n0 + nt * 16 + l15;
            const int cc = gn & 255, h = cc >> 5, d = cc & 31;
            const long bh = (long)b * NH + h;
            const f4 a = acc[mt][nt];
            if (sec == 2) {
                ushort4 vv;
                vv.x = f2bf(a[0]); vv.y = f2bf(a[1]); vv.z = f2bf(a[2]); vv.w = f2bf(a[3]);
                *(ushort4*)(Vt + (bh * HD + d) * TT + tb) = vv;
            } else if (sec == 1) {
                #pragma unroll
                for (int r = 0; r < 4; ++r)
                    Qb[(bh * TT + tb + r) * HD + d] = f2bf(a[r] * 0.25506655788696527f);
            } else {
                #pragma unroll
                for (int r = 0; r < 4; ++r)
                    Kb[(bh * TT + tb + r) * HD + d] = f2bf(a[r]);
            }
        }
    }
}

// ---------------- Kernel B: MFMA flash attention, static-max softmax ---------
// QK accumulator init = -16 (static max). p = exp2(score-16), no rescaling;
// partials stored RAW (unnormalized) + per-row l; merge = (O0+O1)/(l0+l1).
__global__ __launch_bounds__(256) void attn_kernel(const unsigned short* __restrict__ Kb,
                                                   const unsigned short* __restrict__ Qb,
                                                   const unsigned short* __restrict__ Vtg,
                                                   const unsigned short* __restrict__ peb,
                                                   unsigned short* __restrict__ po,
                                                   float* __restrict__ pl) {
    __shared__ unsigned short lds[14592];            // 29184 B
    unsigned short* Ks  = lds;                       // [64][40]  K tile
    unsigned short* PEs = lds + 2560;                // [128][40] pe band
    unsigned short* Vts = lds + 7680;                // [32][72]  V^T tile
    unsigned short* Psw = lds + 9984 + (threadIdx.x >> 6) * 1152;  // [16][72] per wave

    const int tid = threadIdx.x;
    const int wv  = tid >> 6;
    const int L   = tid & 63;
    const int l15 = L & 15;
    const int q   = L >> 4;
    const int pair = blockIdx.x >> 1;
    const int sblk = blockIdx.x & 1;
    const int h = blockIdx.y, b = blockIdx.z;
    const long bh = (long)b * NH + h;
    const unsigned short* Kg = Kb  + bh * TT * HD;
    const unsigned short* Qg = Qb  + bh * TT * HD;
    const unsigned short* Vg = Vtg + bh * HD * TT;
    const unsigned short* Pg = peb + (long)h * TTP * HD;

    const int krow = tid >> 2, kc = tid & 3;
    const int vrow = tid >> 3, vc = tid & 7;
    const f4 z4 = {0.f, 0.f, 0.f, 0.f};
    const f4 m4 = {-16.f, -16.f, -16.f, -16.f};      // static softmax max

    // hoisted skew-gather controls (per r): source lane + perm half-select
    int saddr[4]; unsigned psel[4];
    #pragma unroll
    for (int r = 0; r < 4; ++r) {
        const int tcol = l15 + 15 - 4 * q - r;       // 0..30
        saddr[r] = ((q << 4) | (tcol & 15)) << 2;
        psel[r]  = (tcol < 16) ? 0x01000C0Cu : 0x03020C0Cu;
    }

    for (int half = 0; half < 2; ++half) {
        const int itile = half ? 31 - pair : pair;
        const int t0 = itile * 64;

        const bf8 aq = *(const bf8*)(Qg + (t0 + wv * 16 + l15) * HD + q * 8);
        f4 o0 = z4, o1 = z4;
        float l_st[4] = {0.f, 0.f, 0.f, 0.f};

        for (int jt = sblk; jt <= itile; jt += 2) {
            const int s0 = jt * 64;
            const int ubase = TT - 64 - t0 + s0;     // pe band base (pad rows >= TT are 0)
            __syncthreads();
            *(bf8*)(Ks  + krow * 40 + kc * 8) = *(const bf8*)(Kg + (s0 + krow) * HD + kc * 8);
            *(bf8*)(Vts + vrow * 72 + vc * 8) = *(const bf8*)(Vg + vrow * TT + s0 + vc * 8);
            #pragma unroll
            for (int kk = 0; kk < 2; ++kk) {
                const int i  = tid + kk * 256;
                const int pr = i >> 2, pc = i & 3;
                *(bf8*)(PEs + pr * 40 + pc * 8) = *(const bf8*)(Pg + (long)(ubase + pr) * HD + pc * 8);
            }
            __syncthreads();

            f4 sa[4], ra[5];
            #pragma unroll
            for (int nt = 0; nt < 4; ++nt) {
                const bf8 bk = *(const bf8*)(Ks + (nt * 16 + l15) * 40 + q * 8);
                sa[nt] = __builtin_amdgcn_mfma_f32_16x16x32_bf16(aq, bk, m4, 0, 0, 0);
            }
            const int pebase = 48 - 16 * wv;
            #pragma unroll
            for (int nt = 0; nt < 5; ++nt) {
                const bf8 bp = *(const bf8*)(PEs + (pebase + nt * 16 + l15) * 40 + q * 8);
                ra[nt] = __builtin_amdgcn_mfma_f32_16x16x32_bf16(aq, bp, z4, 0, 0, 0);
            }

            // ---- skew gather: v_perm pack + bpermute + v_perm select ----
            #pragma unroll
            for (int nb = 0; nb < 4; ++nb) {
                #pragma unroll
                for (int r = 0; r < 4; ++r) {
                    const unsigned packed = __builtin_amdgcn_perm(
                        (unsigned)__float_as_int(ra[nb + 1][r]),
                        (unsigned)__float_as_int(ra[nb][r]), 0x07060302u);
                    const int v = __builtin_amdgcn_ds_bpermute(saddr[r], (int)packed);
                    const unsigned sel = __builtin_amdgcn_perm((unsigned)v, (unsigned)v, psel[r]);
                    sa[nb][r] += __int_as_float((int)sel);
                }
            }

            if (jt == itile) {                       // causal mask (diagonal tile)
                #pragma unroll
                for (int nb = 0; nb < 4; ++nb)
                    #pragma unroll
                    for (int r = 0; r < 4; ++r) {
                        const int s_l = nb * 16 + l15;
                        const int t_l = wv * 16 + 4 * q + r;
                        if (s_l > t_l) sa[nb][r] = -1e30f;
                    }
            }

            // ---- static-max softmax: p = exp2(sa); accumulate l per lane ----
            #pragma unroll
            for (int r = 0; r < 4; ++r) {
                #pragma unroll
                for (int nb = 0; nb < 4; ++nb) {
                    const float p = exp2f(sa[nb][r]);
                    l_st[r] += p;
                    const unsigned pu = (unsigned)__float_as_int(p);
                    Psw[(4 * q + r) * 72 + nb * 16 + l15] =
                        (unsigned short)((pu + 0x8000u) >> 16);
                }
            }

            // ---- PV: O += P @ V ----
            #pragma unroll
            for (int ks = 0; ks < 2; ++ks) {
                const bf8 ap  = *(const bf8*)(Psw + l15 * 72 + ks * 32 + q * 8);
                const bf8 bv0 = *(const bf8*)(Vts + l15 * 72 + ks * 32 + q * 8);
                const bf8 bv1 = *(const bf8*)(Vts + (16 + l15) * 72 + ks * 32 + q * 8);
                o0 = __builtin_amdgcn_mfma_f32_16x16x32_bf16(ap, bv0, o0, 0, 0, 0);
                o1 = __builtin_amdgcn_mfma_f32_16x16x32_bf16(ap, bv1, o1, 0, 0, 0);
            }
        }

        // ---- epilogue: raw partial O (bf16) + row l ----
        const long pt = (bh * 32 + itile) * 2 + sblk;
        unsigned short* pob = po + pt * 2048;
        #pragma unroll
        for (int r = 0; r < 4; ++r) {
            const int row = wv * 16 + 4 * q + r;
            pob[row * 32 + l15]      = f2bf(o0[r]);
            pob[row * 32 + 16 + l15] = f2bf(o1[r]);
            const float ls = rowsum16(l_st[r]);
            if (l15 == 0) pl[pt * 64 + row] = ls;
        }
    }
}

// ---------------- merge s-split partials -> bf16 att -------------------------
__global__ __launch_bounds__(256) void attn_merge(const unsigned short* __restrict__ po,
                                                  const float* __restrict__ pl,
                                                  unsigned short* __restrict__ attb) {
    const int i = blockIdx.x * 256 + threadIdx.x;    // 524288 quads
    const int d4   = i & 7;
    const int row  = (i >> 3) & 63;
    const int tile = (i >> 9) & 31;
    const int bh   = i >> 14;
    const int h = bh & 7, b = bh >> 3;
    const long pt0 = ((long)bh * 32 + tile) * 2;
    const float l0 = pl[pt0 * 64 + row], l1 = pl[(pt0 + 1) * 64 + row];
    const float inv = 1.0f / (l0 + l1);
    const ushort4 a = *(const ushort4*)(po + pt0 * 2048 + row * 32 + d4 * 4);
    const ushort4 c = *(const ushort4*)(po + (pt0 + 1) * 2048 + row * 32 + d4 * 4);
    ushort4 o;
    o.x = f2bf((bf2f(a.x) + bf2f(c.x)) * inv);
    o.y = f2bf((bf2f(a.y) + bf2f(c.y)) * inv);
    o.z = f2bf((bf2f(a.z) + bf2f(c.z)) * inv);
    o.w = f2bf((bf2f(a.w) + bf2f(c.w)) * inv);
    const int t = tile * 64 + row;
    *(ushort4*)(attb + ((long)(b * TT + t)) * NEMB + h * HD + d4 * 4) = o;
}

// ---------------- Kernel C: MFMA proj GEMM + bias ----------------------------
__global__ __launch_bounds__(256) void proj_mfma(const unsigned short* __restrict__ Ag,
                                                 const unsigned short* __restrict__ Bg,
                                                 const float* __restrict__ bias,
                                                 float* __restrict__ out) {
    __shared__ unsigned short sm[13824];
    unsigned short* As = sm;                         // [128][72]
    unsigned short* Bs = sm + 9216;                  // [64][72]
    const int tid = threadIdx.x;
    const int wv = tid >> 6, L = tid & 63;
    const int l15 = L & 15, q = L >> 4;
    const int n0 = blockIdx.x * 64;
    const int m0 = blockIdx.y * 128;

    f4 acc[2][4];
    #pragma unroll
    for (int mt = 0; mt < 2; ++mt)
        #pragma unroll
        for (int nt = 0; nt < 4; ++nt) acc[mt][nt] = (f4){0.f,0.f,0.f,0.f};

    for (int kc = 0; kc < 4; ++kc) {
        const int k0 = kc * 64;
        __syncthreads();
        #pragma unroll
        for (int p = 0; p < 4; ++p) {
            const int i = tid + p * 256;
            const int r = i >> 3, c = i & 7;
            *(bf8*)(As + r * 72 + c * 8) = *(const bf8*)(Ag + (long)(m0 + r) * 256 + k0 + c * 8);
        }
        #pragma unroll
        for (int p = 0; p < 2; ++p) {
            const int i = tid + p * 256;
            const int r = i >> 3, c = i & 7;
            *(bf8*)(Bs + r * 72 + c * 8) = *(const bf8*)(Bg + (long)(n0 + r) * 256 + k0 + c * 8);
        }
        __syncthreads();
        #pragma unroll
        for (int kk = 0; kk < 2; ++kk) {
            const bf8 a0 = *(const bf8*)(As + (wv * 32 + l15) * 72 + kk * 32 + q * 8);
            const bf8 a1 = *(const bf8*)(As + (wv * 32 + 16 + l15) * 72 + kk * 32 + q * 8);
            #pragma unroll
            for (int nt = 0; nt < 4; ++nt) {
                const bf8 bb = *(const bf8*)(Bs + (nt * 16 + l15) * 72 + kk * 32 + q * 8);
                acc[0][nt] = __builtin_amdgcn_mfma_f32_16x16x32_bf16(a0, bb, acc[0][nt], 0, 0, 0);
                acc[1][nt] = __builtin_amdgcn_mfma_f32_16x16x32_bf16(a1, bb, acc[1][nt], 0, 0, 0);
            }
        }
    }

    #pragma unroll
    for (int mt = 0; mt < 2; ++mt) {
        const int gm = m0 + wv * 32 + mt * 16 + q * 4;
        #pragma unroll
        for (int nt = 0; nt < 4; ++nt) {
            const int gn = n0 + nt * 16 + l15;
            const float bv = bias[gn];
            #pragma unroll
            for (int r = 0; r < 4; ++r)
                out[(long)(gm + r) * NEMB + gn] = acc[mt][nt][r] + bv;
        }
    }
}

extern "C" void kernel_launch(void* const* d_in, const int* in_sizes, int n_in,
                              void* d_out, int out_size, void* d_ws, size_t ws_size,
                              hipStream_t stream) {
    const float* x      = (const float*)d_in[0];
    const float* w_attn = (const float*)d_in[1];
    const float* pe     = (const float*)d_in[2];
    const float* w_proj = (const float*)d_in[3];
    const float* b_proj = (const float*)d_in[4];
    float* out = (float*)d_out;

    char* base = (char*)d_ws;
    unsigned short* Kb   = (unsigned short*)(base);                        // 4 MB
    unsigned short* Qb   = (unsigned short*)(base + ( 4u << 20));          // 4 MB
    unsigned short* Vt   = (unsigned short*)(base + ( 8u << 20));          // 4 MB
    unsigned short* attb = (unsigned short*)(base + (12u << 20));          // 4 MB
    unsigned short* peb  = (unsigned short*)(base + (16u << 20));          // 1.03 MB
    unsigned short* waT  = (unsigned short*)(base + (18u << 20));          // 384 KB
    unsigned short* wpT  = (unsigned short*)(base + (37u << 19));          // 128 KB @18.5MB
    unsigned short* po   = (unsigned short*)(base + (19u << 20));          // 8 MB
    float*          pl   = (float*)        (base + (27u << 20));           // 512 KB

    prep<<<dim3(592), 256, 0, stream>>>(pe, peb, w_attn, waT, w_proj, wpT);
    qkv_mfma<<<dim3(12, 64), 256, 0, stream>>>(x, waT, Kb, Qb, Vt);
    attn_kernel<<<dim3(32, NH, BB), 256, 0, stream>>>(Kb, Qb, Vt, peb, po, pl);
    attn_merge<<<dim3(2048), 256, 0, stream>>>(po, pl, attb);
    proj_mfma<<<dim3(4, 64), 256, 0, stream>>>(attb, wpT, b_proj, out);
}